// Round 4
// baseline (194.141 us; speedup 1.0000x reference)
//
#include <hip/hip_runtime.h>
#include <math.h>

typedef __bf16 bf16x8 __attribute__((ext_vector_type(8)));
typedef __bf16 bf16x4 __attribute__((ext_vector_type(4)));
typedef float  f32x4  __attribute__((ext_vector_type(4)));

namespace {
constexpr int L_ = 512, D_ = 512, NF = 11;
constexpr long WE = (long)L_ * L_;   // 262144 elems, one 512x512 plane
constexpr long NE = 8 * WE;          // 2097152 elems, B*L*D
constexpr long CPL = 512L * 1024;    // concatenated plane elems (512 rows x 1024)
constexpr float NEGV = -1.0e9f;
constexpr float INV_TEMP = 0.044194173824159216f; // 1/sqrt(512)
}

typedef __attribute__((address_space(1))) void gv_t;
typedef __attribute__((address_space(3))) void lv_t;

__device__ __forceinline__ void async_cp16(const void* g, void* l) {
  __builtin_amdgcn_global_load_lds((gv_t*)g, (lv_t*)l, 16, 0, 0);
}

// ============ fused: 5 projections (z<5, 128x128 dbuf) + feat softmax (z==5) ============
// proj z: 0=qp->qcat[:,0:512] 1=kp->kcat[:,0:512] 2=qfT 3=kfT 4=vp (normal)
__global__ __launch_bounds__(256)
void projfeat_kernel(const __bf16* __restrict__ qkv, const __bf16* __restrict__ Wb,
                     const float* __restrict__ x, const float* __restrict__ imp,
                     const int* __restrict__ lens,
                     __bf16* __restrict__ qcat, __bf16* __restrict__ kcat,
                     __bf16* __restrict__ qfkfT, __bf16* __restrict__ vpb,
                     __bf16* __restrict__ featb)
{
  __shared__ __align__(16) char smem[32768]; // proj: 2x(128x32)A + 2x(128x32)B; feat: 22.5KB
  const int z = blockIdx.z;
  const int tid = threadIdx.x;
  const int wave = tid >> 6, lane = tid & 63;

  if (z < 5) {
    // ---------------- projection GEMM, double-buffered ----------------
    const __bf16* A = qkv + (long)((z == 4) ? 2 : (z & 1)) * NE;
    const __bf16* B = Wb + (long)z * WE;
    __bf16* sA = (__bf16*)smem;          // 2 x 4096 elems
    __bf16* sB = sA + 2 * 4096;          // 2 x 4096 elems
    const int m0 = blockIdx.y * 128, n0 = blockIdx.x * 128;
    const int srow = tid >> 2, scol = (tid & 3) * 8;
    const int quad = lane >> 4, l16 = lane & 15;
    const int wm = (wave >> 1) * 64, wn = (wave & 1) * 64;

    f32x4 acc[4][4];
    #pragma unroll
    for (int i = 0; i < 4; ++i)
      #pragma unroll
      for (int j = 0; j < 4; ++j) acc[i][j] = 0.0f;

    const __bf16* ga = A + (long)(m0 + srow) * 512 + scol;
    const __bf16* gb = B + (long)(n0 + srow) * 512 + scol;
    // preload tile 0 -> buffer 0
    async_cp16(ga,            sA + srow * 32 + scol);
    async_cp16(ga + 64 * 512, sA + (64 + srow) * 32 + scol);
    async_cp16(gb,            sB + srow * 32 + scol);
    async_cp16(gb + 64 * 512, sB + (64 + srow) * 32 + scol);
    __syncthreads();
    int p = 0;
    for (int k0 = 0; k0 < 512; k0 += 32) {
      const int np = p ^ 1;
      if (k0 + 32 < 512) { // prefetch tile k+1 into the other buffer
        async_cp16(ga + k0 + 32,            sA + np * 4096 + srow * 32 + scol);
        async_cp16(ga + 64 * 512 + k0 + 32, sA + np * 4096 + (64 + srow) * 32 + scol);
        async_cp16(gb + k0 + 32,            sB + np * 4096 + srow * 32 + scol);
        async_cp16(gb + 64 * 512 + k0 + 32, sB + np * 4096 + (64 + srow) * 32 + scol);
      }
      const __bf16* rA = sA + p * 4096 + (wm + l16) * 32 + quad * 8;
      const __bf16* rB = sB + p * 4096 + (wn + l16) * 32 + quad * 8;
      bf16x8 af[4], bfr[4];
      #pragma unroll
      for (int i = 0; i < 4; ++i) af[i]  = *(const bf16x8*)(rA + i * 16 * 32);
      #pragma unroll
      for (int j = 0; j < 4; ++j) bfr[j] = *(const bf16x8*)(rB + j * 16 * 32);
      #pragma unroll
      for (int i = 0; i < 4; ++i)
        #pragma unroll
        for (int j = 0; j < 4; ++j)
          acc[i][j] = __builtin_amdgcn_mfma_f32_16x16x32_bf16(af[i], bfr[j], acc[i][j], 0, 0, 0);
      __syncthreads(); // drains prefetch (residual latency) + protects buffer reuse
      p = np;
    }

    // epilogue: C/D col = lane&15, row = quad*4 + reg
    const int quad2 = lane >> 4, l162 = lane & 15;
    #pragma unroll
    for (int i = 0; i < 4; ++i) {
      const int mb = m0 + wm + i * 16 + quad2 * 4;
      #pragma unroll
      for (int j = 0; j < 4; ++j) {
        const int nn = n0 + wn + j * 16 + l162;
        f32x4 c = acc[i][j];
        if (z < 2) {
          __bf16* C = (z == 0) ? qcat : kcat;
          #pragma unroll
          for (int r = 0; r < 4; ++r)
            C[(long)(mb + r) * 1024 + nn] = (__bf16)c[r];
        } else if (z == 4) {
          #pragma unroll
          for (int r = 0; r < 4; ++r)
            vpb[(long)(mb + r) * 512 + nn] = (__bf16)c[r];
        } else {
          __bf16* T = qfkfT + (long)(z - 2) * NE;
          const long bb = (long)(mb >> 9) << 18;
          const int l = mb & 511;
          bf16x4 pk;
          pk[0] = (__bf16)c[0]; pk[1] = (__bf16)c[1];
          pk[2] = (__bf16)c[2]; pk[3] = (__bf16)c[3];
          *(bf16x4*)(T + bb + (long)nn * 512 + l) = pk;
        }
      }
    }
  } else {
    // ---------------- feature-distance softmax (128 blocks, 32 rows each) ----------------
    float* xfs = (float*)smem; // 512*11*4 = 22.5 KB
    const int flat = blockIdx.y * 4 + blockIdx.x; // 0..127
    const int b = flat >> 4;
    const int i0 = (flat & 15) * 32;
    for (int idx = tid; idx < L_ * NF; idx += 256) {
      int j = idx / NF, f = idx - j * NF;
      xfs[idx] = x[((long)b * L_ + j) * D_ + f];
    }
    float im[NF];
    #pragma unroll
    for (int f = 0; f < NF; ++f) im[f] = imp[f];
    const int len = lens[b];
    __syncthreads();
    for (int r = 0; r < 8; ++r) {
      const int i = i0 + wave * 8 + r;
      float xi[NF];
      #pragma unroll
      for (int f = 0; f < NF; ++f) xi[f] = xfs[i * NF + f];
      float l[8];
      float m = -INFINITY;
      #pragma unroll
      for (int t = 0; t < 8; ++t) {
        int j = lane + t * 64;
        float s = 0.f;
        #pragma unroll
        for (int f = 0; f < NF; ++f) s = fmaf(fabsf(xi[f] - xfs[j * NF + f]), im[f], s);
        s = (j < len) ? s : NEGV;
        l[t] = s;
        m = fmaxf(m, s);
      }
      #pragma unroll
      for (int o = 32; o >= 1; o >>= 1) m = fmaxf(m, __shfl_xor(m, o));
      float ssum = 0.f;
      #pragma unroll
      for (int t = 0; t < 8; ++t) { l[t] = expf(l[t] - m); ssum += l[t]; }
      #pragma unroll
      for (int o = 32; o >= 1; o >>= 1) ssum += __shfl_xor(ssum, o);
      float inv = 1.0f / ssum;
      #pragma unroll
      for (int t = 0; t < 8; ++t)
        featb[((long)b * L_ + i) * L_ + lane + t * 64] = (__bf16)(l[t] * inv);
    }
  }
}

// ---------------- 64x128 batched NT core, double-buffered ----------------
// A [512,K] rm stride K, B [512,K] rm stride K. 4 waves, 2x2 of 32x64 tiles.
__device__ __forceinline__ void core64_db(const __bf16* __restrict__ A,
                                          const __bf16* __restrict__ B, int K,
                                          __bf16* sA, __bf16* sB, f32x4 (&acc)[2][4])
{
  const int tid = threadIdx.x;
  const int m0 = blockIdx.y * 64, n0 = blockIdx.x * 128;
  const int srow = tid >> 2, scol = (tid & 3) * 8;
  const int wave = tid >> 6, lane = tid & 63;
  const int quad = lane >> 4, l16 = lane & 15;
  const int wm = (wave >> 1) * 32, wn = (wave & 1) * 64;
  const __bf16* ga = A + (long)(m0 + srow) * K + scol;
  const __bf16* gb = B + (long)(n0 + srow) * K + scol;
  // preload tile 0 -> buffer 0
  async_cp16(ga,                sA + srow * 32 + scol);
  async_cp16(gb,                sB + srow * 32 + scol);
  async_cp16(gb + (long)64 * K, sB + (64 + srow) * 32 + scol);
  __syncthreads();
  int p = 0;
  for (int k0 = 0; k0 < K; k0 += 32) {
    const int np = p ^ 1;
    if (k0 + 32 < K) {
      async_cp16(ga + k0 + 32,                sA + np * 2048 + srow * 32 + scol);
      async_cp16(gb + k0 + 32,                sB + np * 4096 + srow * 32 + scol);
      async_cp16(gb + (long)64 * K + k0 + 32, sB + np * 4096 + (64 + srow) * 32 + scol);
    }
    const __bf16* rA = sA + p * 2048 + (wm + l16) * 32 + quad * 8;
    const __bf16* rB = sB + p * 4096 + (wn + l16) * 32 + quad * 8;
    bf16x8 af[2], bfr[4];
    #pragma unroll
    for (int i = 0; i < 2; ++i) af[i]  = *(const bf16x8*)(rA + i * 16 * 32);
    #pragma unroll
    for (int j = 0; j < 4; ++j) bfr[j] = *(const bf16x8*)(rB + j * 16 * 32);
    #pragma unroll
    for (int i = 0; i < 2; ++i)
      #pragma unroll
      for (int j = 0; j < 4; ++j)
        acc[i][j] = __builtin_amdgcn_mfma_f32_16x16x32_bf16(af[i], bfr[j], acc[i][j], 0, 0, 0);
    __syncthreads();
    p = np;
  }
}

// mega2: z 0..7 qf2 -> qcat[:,512:], z 8..15 kf2 -> kcat[:,512:], z 16..23 vp2T = NT(Wfc, vp[b])
__global__ __launch_bounds__(256)
void mega2_kernel(const __bf16* __restrict__ featb, const __bf16* __restrict__ qfkfT,
                  const __bf16* __restrict__ Wfcb, const __bf16* __restrict__ vpb,
                  __bf16* __restrict__ qcat, __bf16* __restrict__ kcat,
                  __bf16* __restrict__ vp2T)
{
  __shared__ __align__(16) __bf16 sA[2 * 64 * 32];
  __shared__ __align__(16) __bf16 sB[2 * 128 * 32];
  const int z = blockIdx.z;
  const __bf16 *A, *B;
  __bf16* C;
  int ldc;
  if (z < 16) {
    const int b = z & 7, s = z >> 3;
    A = featb + (long)b * WE;
    B = qfkfT + (long)s * NE + (long)b * WE;
    C = (s ? kcat : qcat) + (long)b * CPL + 512;
    ldc = 1024;
  } else {
    const int b = z - 16;
    A = Wfcb;
    B = vpb + (long)b * WE;
    C = vp2T + (long)b * WE;
    ldc = 512;
  }
  f32x4 acc[2][4];
  #pragma unroll
  for (int i = 0; i < 2; ++i)
    #pragma unroll
    for (int j = 0; j < 4; ++j) acc[i][j] = 0.0f;
  core64_db(A, B, 512, sA, sB, acc);

  const int wave = threadIdx.x >> 6, lane = threadIdx.x & 63;
  const int quad = lane >> 4, l16 = lane & 15;
  const int wm = (wave >> 1) * 32, wn = (wave & 1) * 64;
  #pragma unroll
  for (int i = 0; i < 2; ++i) {
    const int mb = blockIdx.y * 64 + wm + i * 16 + quad * 4;
    #pragma unroll
    for (int j = 0; j < 4; ++j) {
      const int nn = blockIdx.x * 128 + wn + j * 16 + l16;
      f32x4 c = acc[i][j];
      #pragma unroll
      for (int r = 0; r < 4; ++r)
        C[(long)(mb + r) * ldc + nn] = (__bf16)c[r];
    }
  }
}

// scores: attn = tanh(mask((qcat . kcat^T)/temp)), K=1024
__global__ __launch_bounds__(256)
void scores_kernel(const __bf16* __restrict__ qcat, const __bf16* __restrict__ kcat,
                   const int* __restrict__ lens, float* __restrict__ attnf,
                   __bf16* __restrict__ attnb)
{
  __shared__ __align__(16) __bf16 sA[2 * 64 * 32];
  __shared__ __align__(16) __bf16 sB[2 * 128 * 32];
  const int b = blockIdx.z;
  const int len = lens[b];
  f32x4 acc[2][4];
  #pragma unroll
  for (int i = 0; i < 2; ++i)
    #pragma unroll
    for (int j = 0; j < 4; ++j) acc[i][j] = 0.0f;
  core64_db(qcat + (long)b * CPL, kcat + (long)b * CPL, 1024, sA, sB, acc);

  const long off = (long)b * WE;
  const int wave = threadIdx.x >> 6, lane = threadIdx.x & 63;
  const int quad = lane >> 4, l16 = lane & 15;
  const int wm = (wave >> 1) * 32, wn = (wave & 1) * 64;
  #pragma unroll
  for (int i = 0; i < 2; ++i) {
    const int mb = blockIdx.y * 64 + wm + i * 16 + quad * 4;
    #pragma unroll
    for (int j = 0; j < 4; ++j) {
      const int nn = blockIdx.x * 128 + wn + j * 16 + l16;
      f32x4 c = acc[i][j];
      #pragma unroll
      for (int r = 0; r < 4; ++r) {
        float v = c[r] * INV_TEMP;
        v = (nn < len) ? tanhf(v) : 0.0f;
        attnf[off + (long)(mb + r) * 512 + nn] = v;
        attnb[off + (long)(mb + r) * 512 + nn] = (__bf16)v;
      }
    }
  }
}

// av2: out2[b] = attn[b] @ vp2[b] (NT with vp2T), fp32 out
__global__ __launch_bounds__(256)
void av2_kernel(const __bf16* __restrict__ attnb, const __bf16* __restrict__ vp2T,
                float* __restrict__ out2)
{
  __shared__ __align__(16) __bf16 sA[2 * 64 * 32];
  __shared__ __align__(16) __bf16 sB[2 * 128 * 32];
  const int b = blockIdx.z;
  f32x4 acc[2][4];
  #pragma unroll
  for (int i = 0; i < 2; ++i)
    #pragma unroll
    for (int j = 0; j < 4; ++j) acc[i][j] = 0.0f;
  core64_db(attnb + (long)b * WE, vp2T + (long)b * WE, 512, sA, sB, acc);

  const long off = (long)b * WE;
  const int wave = threadIdx.x >> 6, lane = threadIdx.x & 63;
  const int quad = lane >> 4, l16 = lane & 15;
  const int wm = (wave >> 1) * 32, wn = (wave & 1) * 64;
  #pragma unroll
  for (int i = 0; i < 2; ++i) {
    const int mb = blockIdx.y * 64 + wm + i * 16 + quad * 4;
    #pragma unroll
    for (int j = 0; j < 4; ++j) {
      const int nn = blockIdx.x * 128 + wn + j * 16 + l16;
      f32x4 c = acc[i][j];
      #pragma unroll
      for (int r = 0; r < 4; ++r)
        out2[off + (long)(mb + r) * 512 + nn] = c[r];
    }
  }
}

// ---------------- fp32 -> bf16 conversion ----------------
struct CvtArgs { const float* s[9]; __bf16* d[9]; int n[9]; };
__global__ __launch_bounds__(256) void cvt_kernel(CvtArgs a)
{
  const int id = blockIdx.y;
  const float* __restrict__ s = a.s[id];
  __bf16* __restrict__ d = a.d[id];
  const int n = a.n[id];
  for (long i = (long)(blockIdx.x * 256 + threadIdx.x) * 4; i < n; i += (long)gridDim.x * 1024) {
    float4 v = *(const float4*)(s + i);
    bf16x4 o;
    o[0] = (__bf16)v.x; o[1] = (__bf16)v.y; o[2] = (__bf16)v.z; o[3] = (__bf16)v.w;
    *(bf16x4*)(d + i) = o;
  }
}

// ---------------- LayerNorm ----------------
__global__ __launch_bounds__(64) void ln_kernel(const float* __restrict__ xin, const float* __restrict__ res,
                                                const float* __restrict__ gamma, const float* __restrict__ beta,
                                                float* __restrict__ out)
{
    const long row = blockIdx.x;
    const int lane = threadIdx.x;
    float v[8];
    float s = 0.f, ss = 0.f;
    #pragma unroll
    for (int t = 0; t < 8; ++t) {
        float u = xin[row * D_ + lane + t * 64] + res[row * D_ + lane + t * 64];
        v[t] = u; s += u; ss = fmaf(u, u, ss);
    }
    #pragma unroll
    for (int o = 32; o >= 1; o >>= 1) { s += __shfl_xor(s, o); ss += __shfl_xor(ss, o); }
    const float mu = s * (1.0f / D_);
    const float var = ss * (1.0f / D_) - mu * mu;
    const float inv = 1.0f / sqrtf(var + 1e-6f);
    #pragma unroll
    for (int t = 0; t < 8; ++t) {
        int d = lane + t * 64;
        out[row * D_ + d] = (v[t] - mu) * inv * gamma[d] + beta[d];
    }
}

extern "C" void kernel_launch(void* const* d_in, const int* in_sizes, int n_in,
                              void* d_out, int out_size, void* d_ws, size_t ws_size,
                              hipStream_t stream) {
    const float* q     = (const float*)d_in[0];
    const float* k     = (const float*)d_in[1];
    const float* v     = (const float*)d_in[2];
    const float* x     = (const float*)d_in[3];
    const int*   lens  = (const int*)d_in[4];
    const float* Wq    = (const float*)d_in[5];
    const float* Wk    = (const float*)d_in[6];
    const float* Wv    = (const float*)d_in[7];
    const float* Wqf   = (const float*)d_in[8];
    const float* Wkf   = (const float*)d_in[9];
    const float* Wfc   = (const float*)d_in[10];
    const float* imp   = (const float*)d_in[11];
    const float* gamma = (const float*)d_in[12];
    const float* beta  = (const float*)d_in[13];

    constexpr long MB = 1 << 20;
    char* w = (char*)d_ws;
    __bf16* qkvb  = (__bf16*)(w);            //  0..12MB : q,k,v bf16
    __bf16* Wb    = (__bf16*)(w + 12 * MB);  // 12..15MB : Wq,Wk,Wqf,Wkf,Wv,Wfc
    __bf16* qfkfT = (__bf16*)(w + 15 * MB);  // 15..23MB : qfT,kfT
    __bf16* vpb   = (__bf16*)(w + 23 * MB);  // 23..27MB : vp
    __bf16* vp2T  = (__bf16*)(w + 27 * MB);  // 27..31MB : vp2T
    __bf16* qcat  = (__bf16*)(w + 31 * MB);  // 31..39MB : [qp | qf2] K=1024
    __bf16* kcat  = (__bf16*)(w + 39 * MB);  // 39..47MB : [kp | kf2]
    __bf16* attnb = (__bf16*)(w + 47 * MB);  // 47..51MB : attn bf16
    float*  out2  = (float*)(w + 51 * MB);   // 51..59MB : pre-LN fp32
    __bf16* featb = (__bf16*)(w + 59 * MB);  // 59..63MB : feat_attn bf16

    float*  outp  = (float*)d_out;           // output 0 [B,L,D]
    float*  attnf = outp + NE;               // output 1 [B,L,L]

    // 1) fp32 -> bf16
    CvtArgs ca;
    ca.s[0] = q;   ca.d[0] = qkvb;          ca.n[0] = (int)NE;
    ca.s[1] = k;   ca.d[1] = qkvb + NE;     ca.n[1] = (int)NE;
    ca.s[2] = v;   ca.d[2] = qkvb + 2 * NE; ca.n[2] = (int)NE;
    ca.s[3] = Wq;  ca.d[3] = Wb;            ca.n[3] = (int)WE;
    ca.s[4] = Wk;  ca.d[4] = Wb + WE;       ca.n[4] = (int)WE;
    ca.s[5] = Wqf; ca.d[5] = Wb + 2 * WE;   ca.n[5] = (int)WE;
    ca.s[6] = Wkf; ca.d[6] = Wb + 3 * WE;   ca.n[6] = (int)WE;
    ca.s[7] = Wv;  ca.d[7] = Wb + 4 * WE;   ca.n[7] = (int)WE;
    ca.s[8] = Wfc; ca.d[8] = Wb + 5 * WE;   ca.n[8] = (int)WE;
    cvt_kernel<<<dim3(512, 9), 256, 0, stream>>>(ca);

    // 2) 5 projections (z<5) + feature softmax (z=5): 768 blocks
    projfeat_kernel<<<dim3(4, 32, 6), 256, 0, stream>>>(qkvb, Wb, x, imp, lens,
                                                        qcat, kcat, qfkfT, vpb, featb);

    // 3) qf2,kf2 -> cat right halves + vp2T = Wfc.vp^T (768 blocks)
    mega2_kernel<<<dim3(4, 8, 24), 256, 0, stream>>>(featb, qfkfT, Wb + 5 * WE, vpb,
                                                     qcat, kcat, vp2T);

    // 4) attn = tanh(mask(qcat.kcat^T / temp)), K=1024 (256 blocks)
    scores_kernel<<<dim3(4, 8, 8), 256, 0, stream>>>(qcat, kcat, lens, attnf, attnb);

    // 5) out2 = attn @ vp2 (256 blocks)
    av2_kernel<<<dim3(4, 8, 8), 256, 0, stream>>>(attnb, vp2T, out2);

    // 6) LayerNorm(out2 + q)
    ln_kernel<<<4096, 64, 0, stream>>>(out2, q, gamma, beta, outp);
}

// Round 5
// 185.017 us; speedup vs baseline: 1.0493x; 1.0493x over previous
//
#include <hip/hip_runtime.h>
#include <math.h>

typedef __bf16 bf16x8 __attribute__((ext_vector_type(8)));
typedef __bf16 bf16x4 __attribute__((ext_vector_type(4)));
typedef float  f32x4  __attribute__((ext_vector_type(4)));

namespace {
constexpr int L_ = 512, D_ = 512, NF = 11;
constexpr long WE = (long)L_ * L_;   // 262144 elems, one 512x512 plane
constexpr long NE = 8 * WE;          // 2097152 elems, B*L*D
constexpr long CPL = 512L * 1024;    // concatenated plane (512 rows x 1024)
constexpr float NEGV = -1.0e9f;
constexpr float INV_TEMP = 0.044194173824159216f; // 1/sqrt(512)
}

typedef __attribute__((address_space(1))) void gv_t;
typedef __attribute__((address_space(3))) void lv_t;

__device__ __forceinline__ void async_cp16(const void* g, void* l) {
  __builtin_amdgcn_global_load_lds((gv_t*)g, (lv_t*)l, 16, 0, 0);
}

// ================= 128x128 projection GEMM, BK=64 (two 32-wide panels) =================
// z: 0=qp->qcat[:,0:512] 1=kp->kcat[:,0:512] 2=qfT 3=kfT 4=vp (normal)
__global__ __launch_bounds__(256)
void proj_kernel(const __bf16* __restrict__ qkv, const __bf16* __restrict__ Wb,
                 __bf16* __restrict__ qcat, __bf16* __restrict__ kcat,
                 __bf16* __restrict__ qfkfT, __bf16* __restrict__ vpb)
{
  __shared__ __align__(16) __bf16 sA[2 * 128 * 32]; // [panel][row][32]
  __shared__ __align__(16) __bf16 sB[2 * 128 * 32];
  const int z = blockIdx.z;
  const __bf16* A = qkv + (long)((z == 4) ? 2 : (z & 1)) * NE;
  const __bf16* B = Wb + (long)z * WE;

  const int tid = threadIdx.x;
  const int wave = tid >> 6, lane = tid & 63;
  const int m0 = blockIdx.y * 128, n0 = blockIdx.x * 128;
  const int prow = wave * 16 + (lane >> 2), pcol = (lane & 3) * 8;
  const int quad = lane >> 4, l16 = lane & 15;
  const int wm = (wave >> 1) * 64, wn = (wave & 1) * 64;

  f32x4 acc[4][4];
  #pragma unroll
  for (int i = 0; i < 4; ++i)
    #pragma unroll
    for (int j = 0; j < 4; ++j) acc[i][j] = 0.0f;

  const __bf16* ga = A + (long)(m0 + prow) * 512 + pcol;
  const __bf16* gb = B + (long)(n0 + prow) * 512 + pcol;
  __bf16* dA = sA + prow * 32 + pcol;
  __bf16* dB = sB + prow * 32 + pcol;

  for (int k0 = 0; k0 < 512; k0 += 64) {
    __syncthreads();
    // A: rows prow, prow+64; panels 0 (k0..k0+31) and 1 (k0+32..k0+63)
    async_cp16(ga + k0,                 dA);
    async_cp16(ga + k0 + 32,            dA + 4096);
    async_cp16(ga + 64 * 512 + k0,      dA + 64 * 32);
    async_cp16(ga + 64 * 512 + k0 + 32, dA + 4096 + 64 * 32);
    async_cp16(gb + k0,                 dB);
    async_cp16(gb + k0 + 32,            dB + 4096);
    async_cp16(gb + 64 * 512 + k0,      dB + 64 * 32);
    async_cp16(gb + 64 * 512 + k0 + 32, dB + 4096 + 64 * 32);
    __syncthreads();
    #pragma unroll
    for (int p = 0; p < 2; ++p) {
      bf16x8 af[4], bfr[4];
      #pragma unroll
      for (int i = 0; i < 4; ++i)
        af[i]  = *(const bf16x8*)(sA + p * 4096 + (wm + i * 16 + l16) * 32 + quad * 8);
      #pragma unroll
      for (int j = 0; j < 4; ++j)
        bfr[j] = *(const bf16x8*)(sB + p * 4096 + (wn + j * 16 + l16) * 32 + quad * 8);
      #pragma unroll
      for (int i = 0; i < 4; ++i)
        #pragma unroll
        for (int j = 0; j < 4; ++j)
          acc[i][j] = __builtin_amdgcn_mfma_f32_16x16x32_bf16(af[i], bfr[j], acc[i][j], 0, 0, 0);
    }
  }

  // epilogue: C/D col = lane&15, row = quad*4 + reg
  #pragma unroll
  for (int i = 0; i < 4; ++i) {
    const int mb = m0 + wm + i * 16 + quad * 4;
    #pragma unroll
    for (int j = 0; j < 4; ++j) {
      const int nn = n0 + wn + j * 16 + l16;
      f32x4 c = acc[i][j];
      if (z < 2) {
        __bf16* C = (z == 0) ? qcat : kcat;
        #pragma unroll
        for (int r = 0; r < 4; ++r)
          C[(long)(mb + r) * 1024 + nn] = (__bf16)c[r];
      } else if (z == 4) {
        #pragma unroll
        for (int r = 0; r < 4; ++r)
          vpb[(long)(mb + r) * 512 + nn] = (__bf16)c[r];
      } else {
        __bf16* T = qfkfT + (long)(z - 2) * NE;
        const long bb = (long)(mb >> 9) << 18;
        const int l = mb & 511;
        bf16x4 pk;
        pk[0] = (__bf16)c[0]; pk[1] = (__bf16)c[1];
        pk[2] = (__bf16)c[2]; pk[3] = (__bf16)c[3];
        *(bf16x4*)(T + bb + (long)nn * 512 + l) = pk;
      }
    }
  }
}

// ================= 64x128 batched NT core, BK=64 panels =================
__device__ __forceinline__ void core_64x128(const __bf16* __restrict__ A,
                                            const __bf16* __restrict__ B, int K,
                                            __bf16* sA, __bf16* sB, f32x4 (&acc)[2][4])
{
  const int tid = threadIdx.x;
  const int wave = tid >> 6, lane = tid & 63;
  const int m0 = blockIdx.y * 64, n0 = blockIdx.x * 128;
  const int prow = wave * 16 + (lane >> 2), pcol = (lane & 3) * 8;
  const int quad = lane >> 4, l16 = lane & 15;
  const int wm = (wave >> 1) * 32, wn = (wave & 1) * 64;
  const __bf16* ga = A + (long)(m0 + prow) * K + pcol;
  const __bf16* gb = B + (long)(n0 + prow) * K + pcol;
  __bf16* dA = sA + prow * 32 + pcol;  // sA: [2][64][32]  (panel stride 2048)
  __bf16* dB = sB + prow * 32 + pcol;  // sB: [2][128][32] (panel stride 4096)
  for (int k0 = 0; k0 < K; k0 += 64) {
    __syncthreads();
    async_cp16(ga + k0,                   dA);
    async_cp16(ga + k0 + 32,              dA + 2048);
    async_cp16(gb + k0,                   dB);
    async_cp16(gb + k0 + 32,              dB + 4096);
    async_cp16(gb + (long)64 * K + k0,      dB + 64 * 32);
    async_cp16(gb + (long)64 * K + k0 + 32, dB + 4096 + 64 * 32);
    __syncthreads();
    #pragma unroll
    for (int p = 0; p < 2; ++p) {
      bf16x8 af[2], bfr[4];
      #pragma unroll
      for (int i = 0; i < 2; ++i)
        af[i]  = *(const bf16x8*)(sA + p * 2048 + (wm + i * 16 + l16) * 32 + quad * 8);
      #pragma unroll
      for (int j = 0; j < 4; ++j)
        bfr[j] = *(const bf16x8*)(sB + p * 4096 + (wn + j * 16 + l16) * 32 + quad * 8);
      #pragma unroll
      for (int i = 0; i < 2; ++i)
        #pragma unroll
        for (int j = 0; j < 4; ++j)
          acc[i][j] = __builtin_amdgcn_mfma_f32_16x16x32_bf16(af[i], bfr[j], acc[i][j], 0, 0, 0);
    }
  }
}

// ================= 64x64 batched NT core, BK=64 panels =================
__device__ __forceinline__ void core_64x64(const __bf16* __restrict__ A,
                                           const __bf16* __restrict__ B, int K,
                                           __bf16* sA, __bf16* sB, f32x4 (&acc)[2][2])
{
  const int tid = threadIdx.x;
  const int wave = tid >> 6, lane = tid & 63;
  const int m0 = blockIdx.y * 64, n0 = blockIdx.x * 64;
  const int prow = wave * 16 + (lane >> 2), pcol = (lane & 3) * 8;
  const int quad = lane >> 4, l16 = lane & 15;
  const int wm = (wave >> 1) * 32, wn = (wave & 1) * 32;
  const __bf16* ga = A + (long)(m0 + prow) * K + pcol;
  const __bf16* gb = B + (long)(n0 + prow) * K + pcol;
  __bf16* dA = sA + prow * 32 + pcol;  // sA,sB: [2][64][32] (panel stride 2048)
  __bf16* dB = sB + prow * 32 + pcol;
  for (int k0 = 0; k0 < K; k0 += 64) {
    __syncthreads();
    async_cp16(ga + k0,      dA);
    async_cp16(ga + k0 + 32, dA + 2048);
    async_cp16(gb + k0,      dB);
    async_cp16(gb + k0 + 32, dB + 2048);
    __syncthreads();
    #pragma unroll
    for (int p = 0; p < 2; ++p) {
      bf16x8 af[2], bfr[2];
      #pragma unroll
      for (int i = 0; i < 2; ++i)
        af[i]  = *(const bf16x8*)(sA + p * 2048 + (wm + i * 16 + l16) * 32 + quad * 8);
      #pragma unroll
      for (int j = 0; j < 2; ++j)
        bfr[j] = *(const bf16x8*)(sB + p * 2048 + (wn + j * 16 + l16) * 32 + quad * 8);
      #pragma unroll
      for (int i = 0; i < 2; ++i)
        #pragma unroll
        for (int j = 0; j < 2; ++j)
          acc[i][j] = __builtin_amdgcn_mfma_f32_16x16x32_bf16(af[i], bfr[j], acc[i][j], 0, 0, 0);
    }
  }
}

// mega2: z 0..7 qf2 -> qcat[:,512:], z 8..15 kf2 -> kcat[:,512:], z 16..23 vp2T = NT(Wfc, vp[b])
__global__ __launch_bounds__(256)
void mega2_kernel(const __bf16* __restrict__ featb, const __bf16* __restrict__ qfkfT,
                  const __bf16* __restrict__ Wfcb, const __bf16* __restrict__ vpb,
                  __bf16* __restrict__ qcat, __bf16* __restrict__ kcat,
                  __bf16* __restrict__ vp2T)
{
  __shared__ __align__(16) __bf16 sA[2 * 64 * 32];
  __shared__ __align__(16) __bf16 sB[2 * 128 * 32];
  const int z = blockIdx.z;
  const __bf16 *A, *B;
  __bf16* C;
  int ldc;
  if (z < 16) {
    const int b = z & 7, s = z >> 3;
    A = featb + (long)b * WE;
    B = qfkfT + (long)s * NE + (long)b * WE;
    C = (s ? kcat : qcat) + (long)b * CPL + 512;
    ldc = 1024;
  } else {
    const int b = z - 16;
    A = Wfcb;
    B = vpb + (long)b * WE;
    C = vp2T + (long)b * WE;
    ldc = 512;
  }
  f32x4 acc[2][4];
  #pragma unroll
  for (int i = 0; i < 2; ++i)
    #pragma unroll
    for (int j = 0; j < 4; ++j) acc[i][j] = 0.0f;
  core_64x128(A, B, 512, sA, sB, acc);

  const int wave = threadIdx.x >> 6, lane = threadIdx.x & 63;
  const int quad = lane >> 4, l16 = lane & 15;
  const int wm = (wave >> 1) * 32, wn = (wave & 1) * 64;
  #pragma unroll
  for (int i = 0; i < 2; ++i) {
    const int mb = blockIdx.y * 64 + wm + i * 16 + quad * 4;
    #pragma unroll
    for (int j = 0; j < 4; ++j) {
      const int nn = blockIdx.x * 128 + wn + j * 16 + l16;
      f32x4 c = acc[i][j];
      #pragma unroll
      for (int r = 0; r < 4; ++r)
        C[(long)(mb + r) * ldc + nn] = (__bf16)c[r];
    }
  }
}

// scores: attn = tanh(mask((qcat . kcat^T)/temp)), K=1024, 64x64 tiles
__global__ __launch_bounds__(256)
void scores_kernel(const __bf16* __restrict__ qcat, const __bf16* __restrict__ kcat,
                   const int* __restrict__ lens, float* __restrict__ attnf,
                   __bf16* __restrict__ attnb)
{
  __shared__ __align__(16) __bf16 sA[2 * 64 * 32];
  __shared__ __align__(16) __bf16 sB[2 * 64 * 32];
  const int b = blockIdx.z;
  const int len = lens[b];
  f32x4 acc[2][2];
  #pragma unroll
  for (int i = 0; i < 2; ++i)
    #pragma unroll
    for (int j = 0; j < 2; ++j) acc[i][j] = 0.0f;
  core_64x64(qcat + (long)b * CPL, kcat + (long)b * CPL, 1024, sA, sB, acc);

  const long off = (long)b * WE;
  const int wave = threadIdx.x >> 6, lane = threadIdx.x & 63;
  const int quad = lane >> 4, l16 = lane & 15;
  const int wm = (wave >> 1) * 32, wn = (wave & 1) * 32;
  #pragma unroll
  for (int i = 0; i < 2; ++i) {
    const int mb = blockIdx.y * 64 + wm + i * 16 + quad * 4;
    #pragma unroll
    for (int j = 0; j < 2; ++j) {
      const int nn = blockIdx.x * 64 + wn + j * 16 + l16;
      f32x4 c = acc[i][j];
      #pragma unroll
      for (int r = 0; r < 4; ++r) {
        float v = c[r] * INV_TEMP;
        v = (nn < len) ? tanhf(v) : 0.0f;
        attnf[off + (long)(mb + r) * 512 + nn] = v;
        attnb[off + (long)(mb + r) * 512 + nn] = (__bf16)v;
      }
    }
  }
}

// av2: out2[b] = attn[b] @ vp2[b] (NT with vp2T), fp32 out, 64x64 tiles
__global__ __launch_bounds__(256)
void av2_kernel(const __bf16* __restrict__ attnb, const __bf16* __restrict__ vp2T,
                float* __restrict__ out2)
{
  __shared__ __align__(16) __bf16 sA[2 * 64 * 32];
  __shared__ __align__(16) __bf16 sB[2 * 64 * 32];
  const int b = blockIdx.z;
  f32x4 acc[2][2];
  #pragma unroll
  for (int i = 0; i < 2; ++i)
    #pragma unroll
    for (int j = 0; j < 2; ++j) acc[i][j] = 0.0f;
  core_64x64(attnb + (long)b * WE, vp2T + (long)b * WE, 512, sA, sB, acc);

  const long off = (long)b * WE;
  const int wave = threadIdx.x >> 6, lane = threadIdx.x & 63;
  const int quad = lane >> 4, l16 = lane & 15;
  const int wm = (wave >> 1) * 32, wn = (wave & 1) * 32;
  #pragma unroll
  for (int i = 0; i < 2; ++i) {
    const int mb = blockIdx.y * 64 + wm + i * 16 + quad * 4;
    #pragma unroll
    for (int j = 0; j < 2; ++j) {
      const int nn = blockIdx.x * 64 + wn + j * 16 + l16;
      f32x4 c = acc[i][j];
      #pragma unroll
      for (int r = 0; r < 4; ++r)
        out2[off + (long)(mb + r) * 512 + nn] = c[r];
    }
  }
}

// ============ fused: fp32->bf16 conversions (z<9) + feature softmax (z==9) ============
struct CvtArgs { const float* s[9]; __bf16* d[9]; int n[9]; };
__global__ __launch_bounds__(256)
void cvtfeat_kernel(CvtArgs a, const float* __restrict__ x, const float* __restrict__ imp,
                    const int* __restrict__ lens, __bf16* __restrict__ featb)
{
  __shared__ float xfs[L_ * NF]; // 22.5 KB (used by feat path only)
  const int z = blockIdx.y;
  const int tid = threadIdx.x;
  if (z < 9) {
    const float* __restrict__ s = a.s[z];
    __bf16* __restrict__ d = a.d[z];
    const int n = a.n[z];
    for (long i = (long)(blockIdx.x * 256 + tid) * 4; i < n; i += 128L * 256 * 4) {
      float4 v = *(const float4*)(s + i);
      bf16x4 o;
      o[0] = (__bf16)v.x; o[1] = (__bf16)v.y; o[2] = (__bf16)v.z; o[3] = (__bf16)v.w;
      *(bf16x4*)(d + i) = o;
    }
  } else {
    const int wave = tid >> 6, lane = tid & 63;
    const int flat = blockIdx.x;          // 0..127
    const int b = flat >> 4;
    const int i0 = (flat & 15) * 32;
    for (int idx = tid; idx < L_ * NF; idx += 256) {
      int j = idx / NF, f = idx - j * NF;
      xfs[idx] = x[((long)b * L_ + j) * D_ + f];
    }
    float im[NF];
    #pragma unroll
    for (int f = 0; f < NF; ++f) im[f] = imp[f];
    const int len = lens[b];
    __syncthreads();
    for (int r = 0; r < 8; ++r) {
      const int i = i0 + wave * 8 + r;
      float xi[NF];
      #pragma unroll
      for (int f = 0; f < NF; ++f) xi[f] = xfs[i * NF + f];
      float l[8];
      float m = -INFINITY;
      #pragma unroll
      for (int t = 0; t < 8; ++t) {
        int j = lane + t * 64;
        float s = 0.f;
        #pragma unroll
        for (int f = 0; f < NF; ++f) s = fmaf(fabsf(xi[f] - xfs[j * NF + f]), im[f], s);
        s = (j < len) ? s : NEGV;
        l[t] = s;
        m = fmaxf(m, s);
      }
      #pragma unroll
      for (int o = 32; o >= 1; o >>= 1) m = fmaxf(m, __shfl_xor(m, o));
      float ssum = 0.f;
      #pragma unroll
      for (int t = 0; t < 8; ++t) { l[t] = expf(l[t] - m); ssum += l[t]; }
      #pragma unroll
      for (int o = 32; o >= 1; o >>= 1) ssum += __shfl_xor(ssum, o);
      float inv = 1.0f / ssum;
      #pragma unroll
      for (int t = 0; t < 8; ++t)
        featb[((long)b * L_ + i) * L_ + lane + t * 64] = (__bf16)(l[t] * inv);
    }
  }
}

// ---------------- LayerNorm: 4 rows per block (one per wave) ----------------
__global__ __launch_bounds__(256) void ln_kernel(const float* __restrict__ xin, const float* __restrict__ res,
                                                 const float* __restrict__ gamma, const float* __restrict__ beta,
                                                 float* __restrict__ out)
{
    const int wave = threadIdx.x >> 6, lane = threadIdx.x & 63;
    const long row = blockIdx.x * 4 + wave;
    float v[8];
    float s = 0.f, ss = 0.f;
    #pragma unroll
    for (int t = 0; t < 8; ++t) {
        float u = xin[row * D_ + lane + t * 64] + res[row * D_ + lane + t * 64];
        v[t] = u; s += u; ss = fmaf(u, u, ss);
    }
    #pragma unroll
    for (int o = 32; o >= 1; o >>= 1) { s += __shfl_xor(s, o); ss += __shfl_xor(ss, o); }
    const float mu = s * (1.0f / D_);
    const float var = ss * (1.0f / D_) - mu * mu;
    const float inv = 1.0f / sqrtf(var + 1e-6f);
    #pragma unroll
    for (int t = 0; t < 8; ++t) {
        int d = lane + t * 64;
        out[row * D_ + d] = (v[t] - mu) * inv * gamma[d] + beta[d];
    }
}

extern "C" void kernel_launch(void* const* d_in, const int* in_sizes, int n_in,
                              void* d_out, int out_size, void* d_ws, size_t ws_size,
                              hipStream_t stream) {
    const float* q     = (const float*)d_in[0];
    const float* k     = (const float*)d_in[1];
    const float* v     = (const float*)d_in[2];
    const float* x     = (const float*)d_in[3];
    const int*   lens  = (const int*)d_in[4];
    const float* Wq    = (const float*)d_in[5];
    const float* Wk    = (const float*)d_in[6];
    const float* Wv    = (const float*)d_in[7];
    const float* Wqf   = (const float*)d_in[8];
    const float* Wkf   = (const float*)d_in[9];
    const float* Wfc   = (const float*)d_in[10];
    const float* imp   = (const float*)d_in[11];
    const float* gamma = (const float*)d_in[12];
    const float* beta  = (const float*)d_in[13];

    constexpr long MB = 1 << 20;
    char* w = (char*)d_ws;
    __bf16* qkvb  = (__bf16*)(w);            //  0..12MB : q,k,v bf16
    __bf16* Wb    = (__bf16*)(w + 12 * MB);  // 12..15MB : Wq,Wk,Wqf,Wkf,Wv,Wfc
    __bf16* qfkfT = (__bf16*)(w + 15 * MB);  // 15..23MB : qfT,kfT
    __bf16* vpb   = (__bf16*)(w + 23 * MB);  // 23..27MB : vp
    __bf16* vp2T  = (__bf16*)(w + 27 * MB);  // 27..31MB : vp2T
    __bf16* qcat  = (__bf16*)(w + 31 * MB);  // 31..39MB : [qp | qf2] K=1024
    __bf16* kcat  = (__bf16*)(w + 39 * MB);  // 39..47MB : [kp | kf2]
    __bf16* attnb = (__bf16*)(w + 47 * MB);  // 47..51MB : attn bf16
    float*  out2  = (float*)(w + 51 * MB);   // 51..59MB : pre-LN fp32
    __bf16* featb = (__bf16*)(w + 59 * MB);  // 59..63MB : feat_attn bf16

    float*  outp  = (float*)d_out;           // output 0 [B,L,D]
    float*  attnf = outp + NE;               // output 1 [B,L,L]

    // 1) fp32 -> bf16 (z<9) + feature softmax (z=9)
    CvtArgs ca;
    ca.s[0] = q;   ca.d[0] = qkvb;          ca.n[0] = (int)NE;
    ca.s[1] = k;   ca.d[1] = qkvb + NE;     ca.n[1] = (int)NE;
    ca.s[2] = v;   ca.d[2] = qkvb + 2 * NE; ca.n[2] = (int)NE;
    ca.s[3] = Wq;  ca.d[3] = Wb;            ca.n[3] = (int)WE;
    ca.s[4] = Wk;  ca.d[4] = Wb + WE;       ca.n[4] = (int)WE;
    ca.s[5] = Wqf; ca.d[5] = Wb + 2 * WE;   ca.n[5] = (int)WE;
    ca.s[6] = Wkf; ca.d[6] = Wb + 3 * WE;   ca.n[6] = (int)WE;
    ca.s[7] = Wv;  ca.d[7] = Wb + 4 * WE;   ca.n[7] = (int)WE;
    ca.s[8] = Wfc; ca.d[8] = Wb + 5 * WE;   ca.n[8] = (int)WE;
    cvtfeat_kernel<<<dim3(128, 10), 256, 0, stream>>>(ca, x, imp, lens, featb);

    // 2) 5 projections (640 blocks, BK=64)
    proj_kernel<<<dim3(4, 32, 5), 256, 0, stream>>>(qkvb, Wb, qcat, kcat, qfkfT, vpb);

    // 3) qf2,kf2 -> cat right halves + vp2T = Wfc.vp^T (768 blocks, BK=64)
    mega2_kernel<<<dim3(4, 8, 24), 256, 0, stream>>>(featb, qfkfT, Wb + 5 * WE, vpb,
                                                     qcat, kcat, vp2T);

    // 4) attn = tanh(mask(qcat.kcat^T / temp)), K=1024 (512 blocks, 64x64)
    scores_kernel<<<dim3(8, 8, 8), 256, 0, stream>>>(qcat, kcat, lens, attnf, attnb);

    // 5) out2 = attn @ vp2 (512 blocks, 64x64)
    av2_kernel<<<dim3(8, 8, 8), 256, 0, stream>>>(attnb, vp2T, out2);

    // 6) LayerNorm(out2 + q)
    ln_kernel<<<1024, 256, 0, stream>>>(out2, q, gamma, beta, outp);
}